// Round 1
// baseline (7036.376 us; speedup 1.0000x reference)
//
#include <hip/hip_runtime.h>
#include <math.h>

// Problem constants
#define B_   64
#define L_   201
#define T_   200
#define E_   512
#define H_   512
#define NQ_  10000
#define G_   2048   // 4*H

__device__ __forceinline__ float sigmoidf_(float x) {
    return 1.0f / (1.0f + __expf(-x));
}
__device__ __forceinline__ float tanhf_(float x) {
    // precise enough (~1e-7 rel for small args), consistent fast path
    return tanhf(x);
}

// ---------------------------------------------------------------------------
// K0: pack W_hh [2048,512] row-major into W4[k][j] = float4{Wi, Wf, Wg, Wo}
//     where Wi = W_hh[j][k], Wf = W_hh[j+512][k], etc.  Layout [512][512] of
//     float4 -> inner-loop loads are 64-lane coalesced dwordx4.
// ---------------------------------------------------------------------------
__global__ __launch_bounds__(256) void pack_whh(const float* __restrict__ Whh,
                                                float4* __restrict__ W4) {
    __shared__ float t[4][32][33];
    int j0 = blockIdx.x * 32, k0 = blockIdx.y * 32;
    int tx = threadIdx.x & 31, ty = threadIdx.x >> 5;  // 32 x 8
#pragma unroll
    for (int g = 0; g < 4; ++g)
#pragma unroll
        for (int s = 0; s < 4; ++s)
            t[g][ty + s * 8][tx] = Whh[(size_t)(g * 512 + j0 + ty + s * 8) * 512 + k0 + tx];
    __syncthreads();
#pragma unroll
    for (int s = 0; s < 4; ++s) {
        int kk = ty + s * 8, jj = tx;
        W4[(size_t)(k0 + kk) * 512 + j0 + jj] =
            make_float4(t[0][jj][kk], t[1][jj][kk], t[2][jj][kk], t[3][jj][kk]);
    }
}

// ---------------------------------------------------------------------------
// K1: xi[m][g] = sum_k emb[x(m)][k] * W_ih[g][k] + b_ih[g] + b_hh[g]
//     m = b*200 + t, x(m) = q[b][t] + NQ * r[b][t].
//     64x64 tile, 256 threads, 4x4 microtile, K-tile 16, LDS [k][row] layout.
// ---------------------------------------------------------------------------
__global__ __launch_bounds__(256) void xi_gemm(const int* __restrict__ q,
                                               const int* __restrict__ r,
                                               const float* __restrict__ emb,
                                               const float* __restrict__ Wih,
                                               const float* __restrict__ bih,
                                               const float* __restrict__ bhh,
                                               float* __restrict__ xi) {
    __shared__ float As[16][68];   // [k][m]
    __shared__ float Bs[16][68];   // [k][n]
    __shared__ int   rowe[64];

    int tid = threadIdx.x;
    int m0 = blockIdx.x * 64, n0 = blockIdx.y * 64;

    if (tid < 64) {
        int m = m0 + tid;
        int b = m / 200, t = m % 200;
        rowe[tid] = q[b * 201 + t] + NQ_ * r[b * 201 + t];
    }
    __syncthreads();

    int tx = tid & 15, ty = tid >> 4;
    int srow = tid >> 2, skq = tid & 3;  // staging: 64 rows x 4 k-quads

    const float* embA = emb + (size_t)rowe[srow] * 512 + skq * 4;
    const float* WihB = Wih + (size_t)(n0 + srow) * 512 + skq * 4;

    float acc[4][4] = {};

    for (int kt = 0; kt < 32; ++kt) {
        int k0 = kt * 16;
        float4 av = *(const float4*)(embA + k0);
        float4 bv = *(const float4*)(WihB + k0);
        __syncthreads();  // previous-iter LDS reads complete
        As[skq * 4 + 0][srow] = av.x;
        As[skq * 4 + 1][srow] = av.y;
        As[skq * 4 + 2][srow] = av.z;
        As[skq * 4 + 3][srow] = av.w;
        Bs[skq * 4 + 0][srow] = bv.x;
        Bs[skq * 4 + 1][srow] = bv.y;
        Bs[skq * 4 + 2][srow] = bv.z;
        Bs[skq * 4 + 3][srow] = bv.w;
        __syncthreads();
#pragma unroll
        for (int kk = 0; kk < 16; ++kk) {
            float4 avec = *(const float4*)&As[kk][ty * 4];
            float4 bvec = *(const float4*)&Bs[kk][tx * 4];
            acc[0][0] += avec.x * bvec.x;
            acc[0][1] += avec.x * bvec.y;
            acc[0][2] += avec.x * bvec.z;
            acc[0][3] += avec.x * bvec.w;
            acc[1][0] += avec.y * bvec.x;
            acc[1][1] += avec.y * bvec.y;
            acc[1][2] += avec.y * bvec.z;
            acc[1][3] += avec.y * bvec.w;
            acc[2][0] += avec.z * bvec.x;
            acc[2][1] += avec.z * bvec.y;
            acc[2][2] += avec.z * bvec.z;
            acc[2][3] += avec.z * bvec.w;
            acc[3][0] += avec.w * bvec.x;
            acc[3][1] += avec.w * bvec.y;
            acc[3][2] += avec.w * bvec.z;
            acc[3][3] += avec.w * bvec.w;
        }
    }

#pragma unroll
    for (int i = 0; i < 4; ++i) {
        int m = m0 + ty * 4 + i;
        int n = n0 + tx * 4;
        float4 o;
        o.x = acc[i][0] + bih[n + 0] + bhh[n + 0];
        o.y = acc[i][1] + bih[n + 1] + bhh[n + 1];
        o.z = acc[i][2] + bih[n + 2] + bhh[n + 2];
        o.w = acc[i][3] + bih[n + 3] + bhh[n + 3];
        *(float4*)&xi[(size_t)m * G_ + n] = o;
    }
}

// ---------------------------------------------------------------------------
// K2: sequential LSTM. One workgroup per batch element (no grid sync).
//     512 threads; thread j owns hidden unit j (gates j, j+512, j+1024, j+1536).
//     h kept in LDS (broadcast reads), c in a register.
// ---------------------------------------------------------------------------
__global__ __launch_bounds__(512) void lstm_seq(const float4* __restrict__ W4,
                                                const float* __restrict__ xi,
                                                float* __restrict__ hs) {
    __shared__ float h_lds[512];
    int j = threadIdx.x;
    int b = blockIdx.x;

    h_lds[j] = 0.0f;
    float c = 0.0f;
    __syncthreads();

    const float* xrow = xi + (size_t)b * T_ * G_;
    float* hrow = hs + (size_t)b * T_ * H_;

    for (int t = 0; t < T_; ++t) {
        float gi = xrow[j];
        float gf = xrow[512 + j];
        float gg = xrow[1024 + j];
        float go = xrow[1536 + j];

        const float4* wp = W4 + j;
#pragma unroll 2
        for (int k0 = 0; k0 < 512; k0 += 4) {
            float4 hv = *(const float4*)&h_lds[k0];
            float4 w0 = wp[(size_t)(k0 + 0) * 512];
            float4 w1 = wp[(size_t)(k0 + 1) * 512];
            float4 w2 = wp[(size_t)(k0 + 2) * 512];
            float4 w3 = wp[(size_t)(k0 + 3) * 512];
            gi += w0.x * hv.x + w1.x * hv.y + w2.x * hv.z + w3.x * hv.w;
            gf += w0.y * hv.x + w1.y * hv.y + w2.y * hv.z + w3.y * hv.w;
            gg += w0.z * hv.x + w1.z * hv.y + w2.z * hv.z + w3.z * hv.w;
            go += w0.w * hv.x + w1.w * hv.y + w2.w * hv.z + w3.w * hv.w;
        }

        float ig = sigmoidf_(gi);
        float fg = sigmoidf_(gf);
        float gc = tanhf_(gg);
        float og = sigmoidf_(go);
        c = fg * c + ig * gc;
        float h = og * tanhf_(c);

        __syncthreads();           // everyone done reading old h
        h_lds[j] = h;
        hrow[j] = h;
        __syncthreads();           // new h visible

        xrow += G_;
        hrow += H_;
    }
}

// ---------------------------------------------------------------------------
// K3: out[m] = sigmoid( dot(hs[m,:], W_out[qshft[m],:]) + b_out[qshft[m]] )
//     One wave per (b,t). Only the gathered rows are ever computed
//     (reference materializes the full [B,T,10000] logits).
// ---------------------------------------------------------------------------
__global__ __launch_bounds__(256) void out_gather(const float* __restrict__ hs,
                                                  const float* __restrict__ Wout,
                                                  const float* __restrict__ bout,
                                                  const int* __restrict__ qshft,
                                                  float* __restrict__ out) {
    int w = threadIdx.x >> 6, l = threadIdx.x & 63;
    int m = blockIdx.x * 4 + w;  // < 12800
    int qs = qshft[m];
    const float* hp = hs + (size_t)m * 512;
    const float* wp = Wout + (size_t)qs * 512;
    float s = 0.0f;
#pragma unroll
    for (int it = 0; it < 2; ++it) {
        int k = (it * 64 + l) * 4;
        float4 hv = *(const float4*)(hp + k);
        float4 wv = *(const float4*)(wp + k);
        s += hv.x * wv.x + hv.y * wv.y + hv.z * wv.z + hv.w * wv.w;
    }
#pragma unroll
    for (int off = 32; off; off >>= 1) s += __shfl_down(s, off);
    if (l == 0) out[m] = sigmoidf_(s + bout[qs]);
}

// ---------------------------------------------------------------------------
extern "C" void kernel_launch(void* const* d_in, const int* in_sizes, int n_in,
                              void* d_out, int out_size, void* d_ws, size_t ws_size,
                              hipStream_t stream) {
    const int*   q    = (const int*)d_in[0];
    // d_in[1] = c (unused by the reference computation)
    const int*   r    = (const int*)d_in[2];
    const int*   qsft = (const int*)d_in[3];
    const float* emb  = (const float*)d_in[4];
    const float* Wih  = (const float*)d_in[5];
    const float* Whh  = (const float*)d_in[6];
    const float* bih  = (const float*)d_in[7];
    const float* bhh  = (const float*)d_in[8];
    const float* Wout = (const float*)d_in[9];
    const float* bout = (const float*)d_in[10];

    float* ws = (float*)d_ws;
    float4* W4 = (float4*)ws;                         // 512*512 float4 = 4 MB
    float*  xi = ws + (size_t)512 * 512 * 4;          // 12800*2048 f32 = 104.9 MB
    float*  hs = xi + (size_t)12800 * 2048;           // 12800*512  f32 = 26.2 MB
    float*  out = (float*)d_out;

    pack_whh<<<dim3(16, 16), 256, 0, stream>>>(Whh, W4);
    xi_gemm<<<dim3(200, 32), 256, 0, stream>>>(q, r, emb, Wih, bih, bhh, xi);
    lstm_seq<<<64, 512, 0, stream>>>(W4, xi, hs);
    out_gather<<<3200, 256, 0, stream>>>(hs, Wout, bout, qsft, out);
}

// Round 2
// 5651.909 us; speedup vs baseline: 1.2450x; 1.2450x over previous
//
#include <hip/hip_runtime.h>
#include <math.h>

// Problem constants
#define B_   64
#define L_   201
#define T_   200
#define E_   512
#define H_   512
#define NQ_  10000
#define G_   2048   // 4*H

#define LSTM_SMEM (131072 + 16384 + 2048)   // hstage 128KB + W 16KB + gate-exchange 2KB

__device__ __forceinline__ float sigmoidf_(float x) {
    return 1.0f / (1.0f + __expf(-x));
}

// ---------------------------------------------------------------------------
// K1: xi[m][g] = sum_k emb[x(m)][k] * W_ih[g][k] + b_ih[g] + b_hh[g]
//     m = b*200 + t, x(m) = q[b][t] + NQ * r[b][t].   (unchanged from R1)
// ---------------------------------------------------------------------------
__global__ __launch_bounds__(256) void xi_gemm(const int* __restrict__ q,
                                               const int* __restrict__ r,
                                               const float* __restrict__ emb,
                                               const float* __restrict__ Wih,
                                               const float* __restrict__ bih,
                                               const float* __restrict__ bhh,
                                               float* __restrict__ xi) {
    __shared__ float As[16][68];   // [k][m]
    __shared__ float Bs[16][68];   // [k][n]
    __shared__ int   rowe[64];

    int tid = threadIdx.x;
    int m0 = blockIdx.x * 64, n0 = blockIdx.y * 64;

    if (tid < 64) {
        int m = m0 + tid;
        int b = m / 200, t = m % 200;
        rowe[tid] = q[b * 201 + t] + NQ_ * r[b * 201 + t];
    }
    __syncthreads();

    int tx = tid & 15, ty = tid >> 4;
    int srow = tid >> 2, skq = tid & 3;  // staging: 64 rows x 4 k-quads

    const float* embA = emb + (size_t)rowe[srow] * 512 + skq * 4;
    const float* WihB = Wih + (size_t)(n0 + srow) * 512 + skq * 4;

    float acc[4][4] = {};

    for (int kt = 0; kt < 32; ++kt) {
        int k0 = kt * 16;
        float4 av = *(const float4*)(embA + k0);
        float4 bv = *(const float4*)(WihB + k0);
        __syncthreads();
        As[skq * 4 + 0][srow] = av.x;
        As[skq * 4 + 1][srow] = av.y;
        As[skq * 4 + 2][srow] = av.z;
        As[skq * 4 + 3][srow] = av.w;
        Bs[skq * 4 + 0][srow] = bv.x;
        Bs[skq * 4 + 1][srow] = bv.y;
        Bs[skq * 4 + 2][srow] = bv.z;
        Bs[skq * 4 + 3][srow] = bv.w;
        __syncthreads();
#pragma unroll
        for (int kk = 0; kk < 16; ++kk) {
            float4 avec = *(const float4*)&As[kk][ty * 4];
            float4 bvec = *(const float4*)&Bs[kk][tx * 4];
            acc[0][0] += avec.x * bvec.x; acc[0][1] += avec.x * bvec.y;
            acc[0][2] += avec.x * bvec.z; acc[0][3] += avec.x * bvec.w;
            acc[1][0] += avec.y * bvec.x; acc[1][1] += avec.y * bvec.y;
            acc[1][2] += avec.y * bvec.z; acc[1][3] += avec.y * bvec.w;
            acc[2][0] += avec.z * bvec.x; acc[2][1] += avec.z * bvec.y;
            acc[2][2] += avec.z * bvec.z; acc[2][3] += avec.z * bvec.w;
            acc[3][0] += avec.w * bvec.x; acc[3][1] += avec.w * bvec.y;
            acc[3][2] += avec.w * bvec.z; acc[3][3] += avec.w * bvec.w;
        }
    }

#pragma unroll
    for (int i = 0; i < 4; ++i) {
        int m = m0 + ty * 4 + i;
        int n = n0 + tx * 4;
        float4 o;
        o.x = acc[i][0] + bih[n + 0] + bhh[n + 0];
        o.y = acc[i][1] + bih[n + 1] + bhh[n + 1];
        o.z = acc[i][2] + bih[n + 2] + bhh[n + 2];
        o.w = acc[i][3] + bih[n + 3] + bhh[n + 3];
        *(float4*)&xi[(size_t)m * G_ + n] = o;
    }
}

// ---------------------------------------------------------------------------
// K2: transpose xi[b*200+t][g]  ->  xiT[t][g][b]   (b innermost for the LSTM)
//     block = (t, g-tile of 256). Reads uncoalesced-but-line-complete,
//     writes coalesced (lane = b).
// ---------------------------------------------------------------------------
__global__ __launch_bounds__(256) void txpose(const float* __restrict__ xi,
                                              float* __restrict__ xiT) {
    __shared__ float ld[256][64];   // 64 KB
    int t = blockIdx.x, g0 = blockIdx.y * 256;
    int b = threadIdx.x >> 2, q = threadIdx.x & 3;
    const float* src = xi + ((size_t)b * 200 + t) * G_ + g0 + q * 64;
#pragma unroll
    for (int i = 0; i < 16; ++i) {
        float4 v = *(const float4*)(src + i * 4);
        int g = q * 64 + i * 4;
        ld[g + 0][b] = v.x; ld[g + 1][b] = v.y;
        ld[g + 2][b] = v.z; ld[g + 3][b] = v.w;
    }
    __syncthreads();
    int bl = threadIdx.x & 63, gw = threadIdx.x >> 6;
    float* dst = xiT + ((size_t)t * G_ + g0) * 64;
    for (int g = gw; g < 256; g += 4)
        dst[(size_t)g * 64 + bl] = ld[g][bl];
}

// ---------------------------------------------------------------------------
// Device-wide hierarchical barrier: 8 monotonic counters (one per bid&7 group
// of 32 WGs). release-RMW arrival, relaxed spin by 8 threads, acquire fence.
// ---------------------------------------------------------------------------
__device__ __forceinline__ void gbar(int* bar, int bid, int tid, int epoch) {
    __syncthreads();   // all WG work (incl. h stores) done
    if (tid == 0)
        __hip_atomic_fetch_add(&bar[(bid & 7) * 16], 1, __ATOMIC_RELEASE,
                               __HIP_MEMORY_SCOPE_AGENT);
    if (tid < 8) {
        int target = epoch * 32;
        while (__hip_atomic_load(&bar[tid * 16], __ATOMIC_RELAXED,
                                 __HIP_MEMORY_SCOPE_AGENT) < target)
            __builtin_amdgcn_s_sleep(1);
    }
    __syncthreads();
    __builtin_amdgcn_fence(__ATOMIC_ACQUIRE, "agent");  // invalidate stale L1/L2
}

__device__ __forceinline__ void gl_lds16(const float* g, float* l) {
    __builtin_amdgcn_global_load_lds(
        (const __attribute__((address_space(1))) void*)g,
        (__attribute__((address_space(3))) void*)l, 16, 0, 0);
}

// ---------------------------------------------------------------------------
// K3: persistent LSTM. 256 WGs x 256 threads; WG owns units u0=2*bid, u0+1.
//     W rows (8x512 = 16KB) live in LDS for all 200 steps. Per step: stage
//     shared h (hb, [128][64] float4 = [k][b]) into LDS, thread (b,grp)
//     computes gate grp of both units, LDS gate exchange, grp<2 update c,h,
//     publish h to hb[(t+1)&1] + hsT[t][u][b], device barrier.
// ---------------------------------------------------------------------------
__global__ void lstm2(const float* __restrict__ Whh,
                      const float* __restrict__ xiT,
                      float4* __restrict__ hb,      // [2][128*64] float4
                      float* __restrict__ hsT,      // [200][512][64]
                      int* __restrict__ bar) {
    extern __shared__ char smem[];
    float4* hst = (float4*)smem;                       // 8192 float4 (128KB)
    float*  Wl  = (float*)(smem + 131072);             // [4][2][512]
    float*  gex = (float*)(smem + 131072 + 16384);     // [4][2][64]

    int tid = threadIdx.x, bid = blockIdx.x;
    int b = tid & 63, grp = tid >> 6;
    int u0 = bid * 2;

    // load the 8 W_hh rows into LDS: Wl[g][uu][k], row = g*512 + u0 + uu
    {
        int row8 = tid >> 5, l32 = tid & 31;
        int g = row8 >> 1, uu = row8 & 1;
        const float* src = Whh + (size_t)(g * 512 + u0 + uu) * 512;
        float* dst = Wl + (g * 2 + uu) * 512;
#pragma unroll
        for (int p = 0; p < 4; ++p)
            *(float4*)(dst + p * 128 + l32 * 4) = *(const float4*)(src + p * 128 + l32 * 4);
    }

    float cst = 0.0f;
    if (grp < 2) {  // zero my slots of h buffer 0 (unit u = u0+grp)
        int u = u0 + grp;
        ((float*)hb)[(((size_t)(u >> 2)) * 64 + b) * 4 + (u & 3)] = 0.0f;
    }
    gbar(bar, bid, tid, 1);   // all zeros + W loads visible

    const float4* wl0 = (const float4*)(Wl + (grp * 2 + 0) * 512);
    const float4* wl1 = (const float4*)(Wl + (grp * 2 + 1) * 512);

    for (int t = 0; t < T_; ++t) {
        // stage h (t&1 buffer) into LDS: 128 chunks of 1KB, 32 per wave
        {
            const float* hbRf = (const float*)(hb + (size_t)(t & 1) * 8192);
            int lane = tid & 63, w = tid >> 6;
#pragma unroll 8
            for (int i = 0; i < 32; ++i) {
                int chunk = w * 32 + i;
                gl_lds16(hbRf + (size_t)chunk * 256 + lane * 4,
                         (float*)(hst + (size_t)chunk * 64));
            }
        }
        // xi gate pre-activations for my 2 rows (issued before the barrier)
        float acc0 = xiT[((size_t)t * G_ + grp * 512 + u0) * 64 + b];
        float acc1 = xiT[((size_t)t * G_ + grp * 512 + u0 + 1) * 64 + b];
        __syncthreads();   // drains vmcnt -> staging + xi complete

#pragma unroll 4
        for (int k4 = 0; k4 < 128; ++k4) {
            float4 hv = hst[k4 * 64 + b];
            float4 w0 = wl0[k4];
            float4 w1 = wl1[k4];
            acc0 += hv.x * w0.x + hv.y * w0.y + hv.z * w0.z + hv.w * w0.w;
            acc1 += hv.x * w1.x + hv.y * w1.y + hv.z * w1.z + hv.w * w1.w;
        }

        float a0 = (grp == 2) ? tanhf(acc0) : sigmoidf_(acc0);
        float a1 = (grp == 2) ? tanhf(acc1) : sigmoidf_(acc1);
        gex[(grp * 2 + 0) * 64 + b] = a0;
        gex[(grp * 2 + 1) * 64 + b] = a1;
        __syncthreads();

        if (grp < 2) {
            int uu = grp, u = u0 + uu;
            float gi = gex[(0 * 2 + uu) * 64 + b];
            float gf = gex[(1 * 2 + uu) * 64 + b];
            float gg = gex[(2 * 2 + uu) * 64 + b];
            float go = gex[(3 * 2 + uu) * 64 + b];
            cst = gf * cst + gi * gg;
            float h = go * tanhf(cst);
            hsT[((size_t)t * 512 + u) * 64 + b] = h;
            if (t < T_ - 1)
                ((float*)(hb + (size_t)((t + 1) & 1) * 8192))
                    [(((size_t)(u >> 2)) * 64 + b) * 4 + (u & 3)] = h;
        }
        if (t < T_ - 1) gbar(bar, bid, tid, t + 2);
    }
}

// ---------------------------------------------------------------------------
// K4: out[b][t] = sigmoid( dot(hsT[t][:][b], W_out[qshft[b][t]]) + b_out[..] )
//     block = one t; lane = b (hsT reads coalesced); Wout rows gathered per
//     lane but line-complete (each lane streams 512B contiguous per kg).
// ---------------------------------------------------------------------------
__global__ __launch_bounds__(256) void out_gather2(const float* __restrict__ hsT,
                                                   const float* __restrict__ Wout,
                                                   const float* __restrict__ bout,
                                                   const int* __restrict__ qshft,
                                                   float* __restrict__ out) {
    __shared__ float red[4][64];
    int t = blockIdx.x;
    int b = threadIdx.x & 63, kg = threadIdx.x >> 6;
    int qs = qshft[b * 200 + t];
    const float* hp = hsT + (size_t)t * 512 * 64 + b;
    const float4* wp = (const float4*)(Wout + (size_t)qs * 512);
    float acc = 0.0f;
    int u0 = kg * 128;
#pragma unroll 8
    for (int u = u0; u < u0 + 128; u += 4) {
        float4 wv = wp[u >> 2];
        acc += hp[(size_t)(u + 0) * 64] * wv.x + hp[(size_t)(u + 1) * 64] * wv.y +
               hp[(size_t)(u + 2) * 64] * wv.z + hp[(size_t)(u + 3) * 64] * wv.w;
    }
    red[kg][b] = acc;
    __syncthreads();
    if (threadIdx.x < 64) {
        int bb = threadIdx.x;
        int qs2 = qshft[bb * 200 + t];
        float s = red[0][bb] + red[1][bb] + red[2][bb] + red[3][bb];
        out[bb * 200 + t] = sigmoidf_(s + bout[qs2]);
    }
}

// ---------------------------------------------------------------------------
extern "C" void kernel_launch(void* const* d_in, const int* in_sizes, int n_in,
                              void* d_out, int out_size, void* d_ws, size_t ws_size,
                              hipStream_t stream) {
    const int*   q    = (const int*)d_in[0];
    // d_in[1] = c (unused by the reference computation)
    const int*   r    = (const int*)d_in[2];
    const int*   qsft = (const int*)d_in[3];
    const float* emb  = (const float*)d_in[4];
    const float* Wih  = (const float*)d_in[5];
    const float* Whh  = (const float*)d_in[6];
    const float* bih  = (const float*)d_in[7];
    const float* bhh  = (const float*)d_in[8];
    const float* Wout = (const float*)d_in[9];
    const float* bout = (const float*)d_in[10];
    float* out = (float*)d_out;

    // workspace layout (bytes):
    //   [0, 1KB)              barrier counters (memset 0 every call)
    //   [1KB, +256KB)         hb: double-buffered h state, [2][128][64] float4
    //   [+,  +26.2MB)         hsT [200][512][64]
    //   [+,  +104.9MB)        xiT [200][2048][64]
    //   [+,  +104.9MB)        xi  [12800][2048]          (total ~236.3 MB)
    char* wsb = (char*)d_ws;
    int*    bar = (int*)wsb;
    float4* hb  = (float4*)(wsb + 1024);
    float*  hsT = (float*)(wsb + 1024 + 262144);
    float*  xiT = (float*)(wsb + 1024 + 262144 + 26214400ull);
    float*  xi  = (float*)(wsb + 1024 + 262144 + 26214400ull + 104857600ull);

    hipMemsetAsync(bar, 0, 1024, stream);

    xi_gemm<<<dim3(200, 32), 256, 0, stream>>>(q, r, emb, Wih, bih, bhh, xi);
    txpose<<<dim3(200, 8), 256, 0, stream>>>(xi, xiT);

    hipFuncSetAttribute((const void*)lstm2,
                        hipFuncAttributeMaxDynamicSharedMemorySize, LSTM_SMEM);
    {
        const float* a0 = Whh; const float* a1 = xiT; float4* a2 = hb;
        float* a3 = hsT; int* a4 = bar;
        void* ka[] = {(void*)&a0, (void*)&a1, (void*)&a2, (void*)&a3, (void*)&a4};
        hipError_t e = hipLaunchCooperativeKernel((const void*)lstm2, dim3(256),
                                                  dim3(256), ka, LSTM_SMEM, stream);
        if (e != hipSuccess) {
            // fallback: plain launch (256 WGs on 256 CUs -> co-resident)
            lstm2<<<256, 256, LSTM_SMEM, stream>>>(Whh, xiT, hb, hsT, bar);
        }
    }

    out_gather2<<<200, 256, 0, stream>>>(hsT, Wout, bout, qsft, out);
}

// Round 3
// 2649.603 us; speedup vs baseline: 2.6556x; 2.1331x over previous
//
#include <hip/hip_runtime.h>
#include <math.h>

// Problem constants
#define B_   64
#define L_   201
#define T_   200
#define E_   512
#define H_   512
#define NQ_  10000
#define G_   2048   // 4*H

// lstm3 geometry: 256 WGs = 32 unit-groups (16 units each) x 8 batch-groups (8 batches each)
#define UGN 32
#define BGN 8
#define LSTM_SMEM (16384 + 65536 + 2048)   // hsl[512][8] + P[32][512] + act[512]

__device__ __forceinline__ float sigmoidf_(float x) {
    return 1.0f / (1.0f + __expf(-x));
}

// ---------------------------------------------------------------------------
// K1: xi[m][g] = sum_k emb[x(m)][k] * W_ih[g][k] + b_ih[g] + b_hh[g]
//     m = b*200 + t, x(m) = q[b][t] + NQ * r[b][t].   (unchanged)
// ---------------------------------------------------------------------------
__global__ __launch_bounds__(256) void xi_gemm(const int* __restrict__ q,
                                               const int* __restrict__ r,
                                               const float* __restrict__ emb,
                                               const float* __restrict__ Wih,
                                               const float* __restrict__ bih,
                                               const float* __restrict__ bhh,
                                               float* __restrict__ xi) {
    __shared__ float As[16][68];   // [k][m]
    __shared__ float Bs[16][68];   // [k][n]
    __shared__ int   rowe[64];

    int tid = threadIdx.x;
    int m0 = blockIdx.x * 64, n0 = blockIdx.y * 64;

    if (tid < 64) {
        int m = m0 + tid;
        int b = m / 200, t = m % 200;
        rowe[tid] = q[b * 201 + t] + NQ_ * r[b * 201 + t];
    }
    __syncthreads();

    int tx = tid & 15, ty = tid >> 4;
    int srow = tid >> 2, skq = tid & 3;

    const float* embA = emb + (size_t)rowe[srow] * 512 + skq * 4;
    const float* WihB = Wih + (size_t)(n0 + srow) * 512 + skq * 4;

    float acc[4][4] = {};

    for (int kt = 0; kt < 32; ++kt) {
        int k0 = kt * 16;
        float4 av = *(const float4*)(embA + k0);
        float4 bv = *(const float4*)(WihB + k0);
        __syncthreads();
        As[skq * 4 + 0][srow] = av.x;
        As[skq * 4 + 1][srow] = av.y;
        As[skq * 4 + 2][srow] = av.z;
        As[skq * 4 + 3][srow] = av.w;
        Bs[skq * 4 + 0][srow] = bv.x;
        Bs[skq * 4 + 1][srow] = bv.y;
        Bs[skq * 4 + 2][srow] = bv.z;
        Bs[skq * 4 + 3][srow] = bv.w;
        __syncthreads();
#pragma unroll
        for (int kk = 0; kk < 16; ++kk) {
            float4 avec = *(const float4*)&As[kk][ty * 4];
            float4 bvec = *(const float4*)&Bs[kk][tx * 4];
            acc[0][0] += avec.x * bvec.x; acc[0][1] += avec.x * bvec.y;
            acc[0][2] += avec.x * bvec.z; acc[0][3] += avec.x * bvec.w;
            acc[1][0] += avec.y * bvec.x; acc[1][1] += avec.y * bvec.y;
            acc[1][2] += avec.y * bvec.z; acc[1][3] += avec.y * bvec.w;
            acc[2][0] += avec.z * bvec.x; acc[2][1] += avec.z * bvec.y;
            acc[2][2] += avec.z * bvec.z; acc[2][3] += avec.z * bvec.w;
            acc[3][0] += avec.w * bvec.x; acc[3][1] += avec.w * bvec.y;
            acc[3][2] += avec.w * bvec.z; acc[3][3] += avec.w * bvec.w;
        }
    }

#pragma unroll
    for (int i = 0; i < 4; ++i) {
        int m = m0 + ty * 4 + i;
        int n = n0 + tx * 4;
        float4 o;
        o.x = acc[i][0] + bih[n + 0] + bhh[n + 0];
        o.y = acc[i][1] + bih[n + 1] + bhh[n + 1];
        o.z = acc[i][2] + bih[n + 2] + bhh[n + 2];
        o.w = acc[i][3] + bih[n + 3] + bhh[n + 3];
        *(float4*)&xi[(size_t)m * G_ + n] = o;
    }
}

// ---------------------------------------------------------------------------
// K2: reshape xi[b*200+t][grow] -> xi4[t][ug][bg][row*8+bl]
//     grow = g*512 + ug*16 + uu ; row = g*16 + uu ; b = bg*8 + bl.
//     Block = (t, ug). LDS tile [64 row][64 b].
// ---------------------------------------------------------------------------
__global__ __launch_bounds__(256) void xi_reshape(const float* __restrict__ xi,
                                                  float* __restrict__ xi4) {
    __shared__ float T[64][68];
    int t = blockIdx.x, ug = blockIdx.y;
    int tid = threadIdx.x;
    int b = tid >> 2, gc = tid & 3;
    const float* src = xi + ((size_t)b * 200 + t) * G_ + gc * 512 + ug * 16;
#pragma unroll
    for (int qq = 0; qq < 4; ++qq) {
        float4 v = *(const float4*)(src + qq * 4);
        int row = gc * 16 + qq * 4;
        T[row + 0][b] = v.x; T[row + 1][b] = v.y;
        T[row + 2][b] = v.z; T[row + 3][b] = v.w;
    }
    __syncthreads();
    float* dst = xi4 + ((size_t)t * UGN + ug) * (BGN * 512);
#pragma unroll
    for (int c4 = 0; c4 < 4; ++c4) {
        int d = tid * 16 + c4 * 4;
        int bg = d >> 9, row = (d >> 3) & 63, bl = d & 7;
        float4 v = *(const float4*)&T[row][bg * 8 + bl];
        *(float4*)&dst[d] = v;
    }
}

// ---------------------------------------------------------------------------
// K3: persistent LSTM, fence-free.
//   WG (ug,bg): units u = ug*16..+15 (rows row = g*16+uu, 64 rows),
//   batches b = bg*8..+7. Threads 256: s = tid>>3 (32 k-slices of 16),
//   rt = tid&7 (8 rows each). W_hh in VGPRs (128/thread). h staged in LDS
//   via sc0sc1 loads; partial sums reduced through LDS; h exchanged through
//   a coherent (sc0sc1) global buffer; 8 independent 32-WG spin barriers.
// ---------------------------------------------------------------------------
__global__ __launch_bounds__(256, 1) void lstm3(const float* __restrict__ Whh,
                                                const float* __restrict__ xi4,
                                                float* __restrict__ hb,   // [2][8][512][8]
                                                float* __restrict__ hsT,  // [200][512][64]
                                                int* __restrict__ bar) {
    extern __shared__ float sm[];
    float* hsl = sm;              // [512][8], rows k stored at k ^ ((k>>4)&3)
    float* P   = sm + 4096;       // [32 s][512], chunk c stored at c ^ (s&7)
    float* act = sm + 4096 + 16384;  // [512] = [g*16+uu][bl]

    const int tid = threadIdx.x;
    const int bid = blockIdx.x;
    const int ug = bid >> 3, bg = bid & 7;
    const int s = tid >> 3, rt = tid & 7;

    // ---- W_hh into registers: Wreg[i][kk] = Whh[g*512 + ug*16 + uu][s*16+kk]
    //      row = rt*8+i, g = rt>>1, uu = (rt&1)*8 + i
    float Wreg[8][16];
    {
        const int g = rt >> 1;
#pragma unroll
        for (int i = 0; i < 8; ++i) {
            const int uu = (rt & 1) * 8 + i;
            const float* wr = Whh + (size_t)(g * 512 + ug * 16 + uu) * 512 + s * 16;
            float4 w0 = *(const float4*)(wr + 0);
            float4 w1 = *(const float4*)(wr + 4);
            float4 w2 = *(const float4*)(wr + 8);
            float4 w3 = *(const float4*)(wr + 12);
            Wreg[i][0] = w0.x;  Wreg[i][1] = w0.y;  Wreg[i][2] = w0.z;  Wreg[i][3] = w0.w;
            Wreg[i][4] = w1.x;  Wreg[i][5] = w1.y;  Wreg[i][6] = w1.z;  Wreg[i][7] = w1.w;
            Wreg[i][8] = w2.x;  Wreg[i][9] = w2.y;  Wreg[i][10] = w2.z; Wreg[i][11] = w2.w;
            Wreg[i][12] = w3.x; Wreg[i][13] = w3.y; Wreg[i][14] = w3.z; Wreg[i][15] = w3.w;
        }
    }

    float cst = 0.0f;  // c-state (finalize threads tid<128: uu = tid>>3, bl = tid&7)

    const int o0 = tid * 2;            // reduce outputs o0, o0+1
    const int rrt = o0 >> 6;
    const int cc = (o0 >> 2) & 15;
    const int jj = o0 & 3;
    const int ggate = o0 >> 7;

    for (int t = 0; t < T_; ++t) {
        // ---- xi prefetch for reduce phase (normal cached loads, issued early)
        const float* xig = xi4 + (((size_t)t * UGN + ug) * BGN + bg) * 512;
        const float xv0 = xig[o0];
        const float xv1 = xig[o0 + 1];

        // ---- stage own-bg h slice: 16 floats/thread, coherent loads
        {
            const float* src = hb + ((size_t)(t & 1) * BGN + bg) * 512 * 8 + tid * 16;
            float4 a, b, c, d;
            asm volatile(
                "global_load_dwordx4 %0, %4, off sc0 sc1\n\t"
                "global_load_dwordx4 %1, %4, off offset:16 sc0 sc1\n\t"
                "global_load_dwordx4 %2, %4, off offset:32 sc0 sc1\n\t"
                "global_load_dwordx4 %3, %4, off offset:48 sc0 sc1\n\t"
                "s_waitcnt vmcnt(0)"
                : "=v"(a), "=v"(b), "=v"(c), "=v"(d)
                : "v"(src)
                : "memory");
            const int k0 = tid * 2, k1 = k0 + 1;
            const int kx0 = k0 ^ ((k0 >> 4) & 3);
            const int kx1 = k1 ^ ((k1 >> 4) & 3);
            *(float4*)&hsl[kx0 * 8 + 0] = a;
            *(float4*)&hsl[kx0 * 8 + 4] = b;
            *(float4*)&hsl[kx1 * 8 + 0] = c;
            *(float4*)&hsl[kx1 * 8 + 4] = d;
        }
        __syncthreads();

        // ---- FMA phase: acc[i][j] += W[row][k] * h[k][b0+j], k = s*16..+15
        float acc[8][8] = {};
        {
            const int sx = s & 3;
#pragma unroll
            for (int kk = 0; kk < 16; ++kk) {
                const int kx = (s * 16 + kk) ^ sx;
                float4 hA = *(float4*)&hsl[kx * 8 + 0];
                float4 hB = *(float4*)&hsl[kx * 8 + 4];
#pragma unroll
                for (int i = 0; i < 8; ++i) {
                    const float w = Wreg[i][kk];
                    acc[i][0] += w * hA.x; acc[i][1] += w * hA.y;
                    acc[i][2] += w * hA.z; acc[i][3] += w * hA.w;
                    acc[i][4] += w * hB.x; acc[i][5] += w * hB.y;
                    acc[i][6] += w * hB.z; acc[i][7] += w * hB.w;
                }
            }
        }

        // ---- write partials: P[s][rt*64 + (c ^ (s&7))*4 + j]
        {
            float* Pr = P + s * 512 + rt * 64;
            const int sw = s & 7;
#pragma unroll
            for (int i = 0; i < 8; ++i) {
                const int c0 = (i * 2) ^ sw;
                const int c1 = (i * 2 + 1) ^ sw;
                *(float4*)&Pr[c0 * 4] = make_float4(acc[i][0], acc[i][1], acc[i][2], acc[i][3]);
                *(float4*)&Pr[c1 * 4] = make_float4(acc[i][4], acc[i][5], acc[i][6], acc[i][7]);
            }
        }
        __syncthreads();

        // ---- reduce over 32 slices + xi + activation
        {
            float s0 = xv0, s1 = xv1;
            const float* Pc = P + rrt * 64 + jj;
#pragma unroll 8
            for (int ss = 0; ss < 32; ++ss) {
                const float* p = Pc + ss * 512 + ((cc ^ (ss & 7)) << 2);
                s0 += p[0];
                s1 += p[1];
            }
            float a0, a1;
            if (ggate == 2) { a0 = tanhf(s0); a1 = tanhf(s1); }
            else            { a0 = sigmoidf_(s0); a1 = sigmoidf_(s1); }
            act[o0] = a0;
            act[o0 + 1] = a1;
        }
        __syncthreads();

        // ---- finalize: c,h update for (uu, bl); publish h
        if (tid < 128) {
            const int uu = tid >> 3, bl = tid & 7;
            const float gi = act[(0 * 16 + uu) * 8 + bl];
            const float gf = act[(1 * 16 + uu) * 8 + bl];
            const float gG = act[(2 * 16 + uu) * 8 + bl];
            const float go = act[(3 * 16 + uu) * 8 + bl];
            cst = gf * cst + gi * gG;
            const float h = go * tanhf(cst);
            const int uglob = ug * 16 + uu;
            hsT[((size_t)t * 512 + uglob) * 64 + bg * 8 + bl] = h;
            if (t < T_ - 1) {
                float* dst = hb + (((size_t)((t + 1) & 1) * BGN + bg) * 512 + uglob) * 8 + bl;
                asm volatile("global_store_dword %0, %1, off sc0 sc1"
                             :: "v"(dst), "v"(h) : "memory");
            }
            asm volatile("s_waitcnt vmcnt(0)" ::: "memory");
        }

        // ---- bg-local grid barrier (32 WGs), relaxed atomics, no cache fences
        if (t < T_ - 1) {
            __syncthreads();   // all waves' stores drained (pre-barrier vmcnt(0))
            if (tid == 0) {
                __hip_atomic_fetch_add(&bar[bg * 32], 1, __ATOMIC_RELAXED,
                                       __HIP_MEMORY_SCOPE_AGENT);
                const int target = 32 * (t + 1);
                while (__hip_atomic_load(&bar[bg * 32], __ATOMIC_RELAXED,
                                         __HIP_MEMORY_SCOPE_AGENT) < target)
                    __builtin_amdgcn_s_sleep(2);
            }
            __syncthreads();
        }
    }
}

// ---------------------------------------------------------------------------
// K4: out[b][t] = sigmoid( dot(hsT[t][:][b], W_out[qshft[b][t]]) + b_out[..] )
// ---------------------------------------------------------------------------
__global__ __launch_bounds__(256) void out_gather2(const float* __restrict__ hsT,
                                                   const float* __restrict__ Wout,
                                                   const float* __restrict__ bout,
                                                   const int* __restrict__ qshft,
                                                   float* __restrict__ out) {
    __shared__ float red[4][64];
    int t = blockIdx.x;
    int b = threadIdx.x & 63, kg = threadIdx.x >> 6;
    int qs = qshft[b * 200 + t];
    const float* hp = hsT + (size_t)t * 512 * 64 + b;
    const float4* wp = (const float4*)(Wout + (size_t)qs * 512);
    float acc = 0.0f;
    int u0 = kg * 128;
#pragma unroll 8
    for (int u = u0; u < u0 + 128; u += 4) {
        float4 wv = wp[u >> 2];
        acc += hp[(size_t)(u + 0) * 64] * wv.x + hp[(size_t)(u + 1) * 64] * wv.y +
               hp[(size_t)(u + 2) * 64] * wv.z + hp[(size_t)(u + 3) * 64] * wv.w;
    }
    red[kg][b] = acc;
    __syncthreads();
    if (threadIdx.x < 64) {
        int bb = threadIdx.x;
        int qs2 = qshft[bb * 200 + t];
        float sum = red[0][bb] + red[1][bb] + red[2][bb] + red[3][bb];
        out[bb * 200 + t] = sigmoidf_(sum + bout[qs2]);
    }
}

// ---------------------------------------------------------------------------
extern "C" void kernel_launch(void* const* d_in, const int* in_sizes, int n_in,
                              void* d_out, int out_size, void* d_ws, size_t ws_size,
                              hipStream_t stream) {
    const int*   q    = (const int*)d_in[0];
    // d_in[1] = c (unused by the reference computation)
    const int*   r    = (const int*)d_in[2];
    const int*   qsft = (const int*)d_in[3];
    const float* emb  = (const float*)d_in[4];
    const float* Wih  = (const float*)d_in[5];
    const float* Whh  = (const float*)d_in[6];
    const float* bih  = (const float*)d_in[7];
    const float* bhh  = (const float*)d_in[8];
    const float* Wout = (const float*)d_in[9];
    const float* bout = (const float*)d_in[10];
    float* out = (float*)d_out;

    // workspace layout (bytes):
    //   [0, 1KB)        barrier counters        (memset 0 every call)
    //   [1KB, +256KB)   hb [2][8][512][8] f32   (memset 0: t=0 state)
    //   [+, +26.2MB)    hsT [200][512][64]
    //   [+, +104.9MB)   xi4 [200][32][8][512]
    //   [+, +104.9MB)   xi  [12800][2048]        (total ~236.3 MB)
    char* wsb = (char*)d_ws;
    int*   bar = (int*)wsb;
    float* hb  = (float*)(wsb + 1024);
    float* hsT = (float*)(wsb + 1024 + 262144);
    float* xi4 = (float*)(wsb + 1024 + 262144 + 26214400ull);
    float* xi  = (float*)(wsb + 1024 + 262144 + 26214400ull + 104857600ull);

    hipMemsetAsync(wsb, 0, 1024 + 262144, stream);

    xi_gemm<<<dim3(200, 32), 256, 0, stream>>>(q, r, emb, Wih, bih, bhh, xi);
    xi_reshape<<<dim3(200, 32), 256, 0, stream>>>(xi, xi4);

    hipFuncSetAttribute((const void*)lstm3,
                        hipFuncAttributeMaxDynamicSharedMemorySize, LSTM_SMEM);
    {
        const float* a0 = Whh; const float* a1 = xi4; float* a2 = hb;
        float* a3 = hsT; int* a4 = bar;
        void* ka[] = {(void*)&a0, (void*)&a1, (void*)&a2, (void*)&a3, (void*)&a4};
        hipError_t e = hipLaunchCooperativeKernel((const void*)lstm3, dim3(256),
                                                  dim3(256), ka, LSTM_SMEM, stream);
        if (e != hipSuccess) {
            // fallback: plain launch (256 WGs, 1/CU due to LDS -> all co-resident)
            lstm3<<<256, 256, LSTM_SMEM, stream>>>(Whh, xi4, hb, hsT, bar);
        }
    }

    out_gather2<<<200, 256, 0, stream>>>(hsT, Wout, bout, qsft, out);
}

// Round 4
// 2611.299 us; speedup vs baseline: 2.6946x; 1.0147x over previous
//
#include <hip/hip_runtime.h>
#include <math.h>

// Problem constants
#define B_   64
#define L_   201
#define T_   200
#define E_   512
#define H_   512
#define NQ_  10000
#define G_   2048   // 4*H

// lstm geometry: 256 WGs = 32 unit-groups (16 units each) x 8 batch-groups (8 batches each)
#define UGN 32
#define BGN 8
#define LSTM_SMEM (16384 + 65536 + 2048)   // hsl[512][8] + P[32][512] + act[512]

__device__ __forceinline__ float sigmoidf_(float x) {
    return 1.0f / (1.0f + __expf(-x));
}

// ---------------------------------------------------------------------------
// K1: xi[m][g] = sum_k emb[x(m)][k] * W_ih[g][k] + b_ih[g] + b_hh[g]
//     m = b*200 + t, x(m) = q[b][t] + NQ * r[b][t].   (unchanged)
// ---------------------------------------------------------------------------
__global__ __launch_bounds__(256) void xi_gemm(const int* __restrict__ q,
                                               const int* __restrict__ r,
                                               const float* __restrict__ emb,
                                               const float* __restrict__ Wih,
                                               const float* __restrict__ bih,
                                               const float* __restrict__ bhh,
                                               float* __restrict__ xi) {
    __shared__ float As[16][68];   // [k][m]
    __shared__ float Bs[16][68];   // [k][n]
    __shared__ int   rowe[64];

    int tid = threadIdx.x;
    int m0 = blockIdx.x * 64, n0 = blockIdx.y * 64;

    if (tid < 64) {
        int m = m0 + tid;
        int b = m / 200, t = m % 200;
        rowe[tid] = q[b * 201 + t] + NQ_ * r[b * 201 + t];
    }
    __syncthreads();

    int tx = tid & 15, ty = tid >> 4;
    int srow = tid >> 2, skq = tid & 3;

    const float* embA = emb + (size_t)rowe[srow] * 512 + skq * 4;
    const float* WihB = Wih + (size_t)(n0 + srow) * 512 + skq * 4;

    float acc[4][4] = {};

    for (int kt = 0; kt < 32; ++kt) {
        int k0 = kt * 16;
        float4 av = *(const float4*)(embA + k0);
        float4 bv = *(const float4*)(WihB + k0);
        __syncthreads();
        As[skq * 4 + 0][srow] = av.x;
        As[skq * 4 + 1][srow] = av.y;
        As[skq * 4 + 2][srow] = av.z;
        As[skq * 4 + 3][srow] = av.w;
        Bs[skq * 4 + 0][srow] = bv.x;
        Bs[skq * 4 + 1][srow] = bv.y;
        Bs[skq * 4 + 2][srow] = bv.z;
        Bs[skq * 4 + 3][srow] = bv.w;
        __syncthreads();
#pragma unroll
        for (int kk = 0; kk < 16; ++kk) {
            float4 avec = *(const float4*)&As[kk][ty * 4];
            float4 bvec = *(const float4*)&Bs[kk][tx * 4];
            acc[0][0] += avec.x * bvec.x; acc[0][1] += avec.x * bvec.y;
            acc[0][2] += avec.x * bvec.z; acc[0][3] += avec.x * bvec.w;
            acc[1][0] += avec.y * bvec.x; acc[1][1] += avec.y * bvec.y;
            acc[1][2] += avec.y * bvec.z; acc[1][3] += avec.y * bvec.w;
            acc[2][0] += avec.z * bvec.x; acc[2][1] += avec.z * bvec.y;
            acc[2][2] += avec.z * bvec.z; acc[2][3] += avec.z * bvec.w;
            acc[3][0] += avec.w * bvec.x; acc[3][1] += avec.w * bvec.y;
            acc[3][2] += avec.w * bvec.z; acc[3][3] += avec.w * bvec.w;
        }
    }

#pragma unroll
    for (int i = 0; i < 4; ++i) {
        int m = m0 + ty * 4 + i;
        int n = n0 + tx * 4;
        float4 o;
        o.x = acc[i][0] + bih[n + 0] + bhh[n + 0];
        o.y = acc[i][1] + bih[n + 1] + bhh[n + 1];
        o.z = acc[i][2] + bih[n + 2] + bhh[n + 2];
        o.w = acc[i][3] + bih[n + 3] + bhh[n + 3];
        *(float4*)&xi[(size_t)m * G_ + n] = o;
    }
}

// ---------------------------------------------------------------------------
// K2: reshape xi[b*200+t][grow] -> xi4[t][ug][bg][row*8+bl]   (unchanged)
// ---------------------------------------------------------------------------
__global__ __launch_bounds__(256) void xi_reshape(const float* __restrict__ xi,
                                                  float* __restrict__ xi4) {
    __shared__ float T[64][68];
    int t = blockIdx.x, ug = blockIdx.y;
    int tid = threadIdx.x;
    int b = tid >> 2, gc = tid & 3;
    const float* src = xi + ((size_t)b * 200 + t) * G_ + gc * 512 + ug * 16;
#pragma unroll
    for (int qq = 0; qq < 4; ++qq) {
        float4 v = *(const float4*)(src + qq * 4);
        int row = gc * 16 + qq * 4;
        T[row + 0][b] = v.x; T[row + 1][b] = v.y;
        T[row + 2][b] = v.z; T[row + 3][b] = v.w;
    }
    __syncthreads();
    float* dst = xi4 + ((size_t)t * UGN + ug) * (BGN * 512);
#pragma unroll
    for (int c4 = 0; c4 < 4; ++c4) {
        int d = tid * 16 + c4 * 4;
        int bg = d >> 9, row = (d >> 3) & 63, bl = d & 7;
        float4 v = *(const float4*)&T[row][bg * 8 + bl];
        *(float4*)&dst[d] = v;
    }
}

// ---------------------------------------------------------------------------
// K3: persistent LSTM (lstm4).
//   WG (ug,bg): units ug*16..+16, batches bg*8..+8. FMA layout as R3
//   (s=tid>>3 k-slice of 16, rt=tid&7 -> 8 rows, W in 128 VGPRs).
//   New: conflict-free reduce (o = tid, tid+256), flag-based barrier
//   (per-WG release flag + 32-lane parallel poll, no RMW contention).
// ---------------------------------------------------------------------------
__global__ __launch_bounds__(256, 1) void lstm4(const float* __restrict__ Whh,
                                                const float* __restrict__ xi4,
                                                float* __restrict__ hb,   // [2][8][512][8]
                                                float* __restrict__ hsT,  // [200][512][64]
                                                int* __restrict__ bar) {
    extern __shared__ float sm[];
    float* hsl = sm;                 // [512][8], row k stored at k ^ ((k>>4)&3)
    float* P   = sm + 4096;          // [32][512], chunk c stored at c ^ (s&7)
    float* act = sm + 4096 + 16384;  // [512] = [gate*128 + uu*8 + bl]

    const int tid = threadIdx.x;
    const int bid = blockIdx.x;
    const int ug = bid >> 3, bg = bid & 7;
    const int s = tid >> 3, rt = tid & 7;

    // ---- W_hh into registers: Wreg[i][kk] = Whh[g*512 + ug*16 + uu][s*16+kk]
    //      row = rt*8+i, g = rt>>1, uu = (rt&1)*8 + i
    float Wreg[8][16];
    {
        const int g = rt >> 1;
#pragma unroll
        for (int i = 0; i < 8; ++i) {
            const int uu = (rt & 1) * 8 + i;
            const float* wr = Whh + (size_t)(g * 512 + ug * 16 + uu) * 512 + s * 16;
            float4 w0 = *(const float4*)(wr + 0);
            float4 w1 = *(const float4*)(wr + 4);
            float4 w2 = *(const float4*)(wr + 8);
            float4 w3 = *(const float4*)(wr + 12);
            Wreg[i][0] = w0.x;  Wreg[i][1] = w0.y;  Wreg[i][2] = w0.z;  Wreg[i][3] = w0.w;
            Wreg[i][4] = w1.x;  Wreg[i][5] = w1.y;  Wreg[i][6] = w1.z;  Wreg[i][7] = w1.w;
            Wreg[i][8] = w2.x;  Wreg[i][9] = w2.y;  Wreg[i][10] = w2.z; Wreg[i][11] = w2.w;
            Wreg[i][12] = w3.x; Wreg[i][13] = w3.y; Wreg[i][14] = w3.z; Wreg[i][15] = w3.w;
        }
    }

    float cst = 0.0f;                 // c-state for finalize threads (tid<128)
    const bool isTanh = (tid < 128);  // o2 = tid+256 is gate 2 (g) iff tid<128

    int* myflag = bar + (bg * 32 + ug) * 8;

    for (int t = 0; t < T_; ++t) {
        // ---- xi pre-activations for my two outputs (cached loads, issued early)
        const float* xig = xi4 + (((size_t)t * UGN + ug) * BGN + bg) * 512;
        const float xv1 = xig[tid];
        const float xv2 = xig[tid + 256];

        // ---- stage own-bg h slice (16 floats/thread), coherent loads
        {
            const float* src = hb + ((size_t)(t & 1) * BGN + bg) * 4096 + tid * 16;
            float4 a, b, c, d;
            asm volatile(
                "global_load_dwordx4 %0, %4, off sc0 sc1\n\t"
                "global_load_dwordx4 %1, %4, off offset:16 sc0 sc1\n\t"
                "global_load_dwordx4 %2, %4, off offset:32 sc0 sc1\n\t"
                "global_load_dwordx4 %3, %4, off offset:48 sc0 sc1\n\t"
                "s_waitcnt vmcnt(0)"
                : "=v"(a), "=v"(b), "=v"(c), "=v"(d)
                : "v"(src)
                : "memory");
            const int k0 = tid * 2, k1 = k0 + 1;
            const int kx0 = k0 ^ ((k0 >> 4) & 3);
            const int kx1 = k1 ^ ((k1 >> 4) & 3);
            *(float4*)&hsl[kx0 * 8 + 0] = a;
            *(float4*)&hsl[kx0 * 8 + 4] = b;
            *(float4*)&hsl[kx1 * 8 + 0] = c;
            *(float4*)&hsl[kx1 * 8 + 4] = d;
        }
        __syncthreads();

        // ---- FMA phase: acc[i][j] += W[row][k] * h[k][j], k = s*16..+15
        float acc[8][8] = {};
        {
            const int sx = s & 3;
#pragma unroll
            for (int kk = 0; kk < 16; ++kk) {
                const int kx = (s * 16 + kk) ^ sx;
                float4 hA = *(float4*)&hsl[kx * 8 + 0];
                float4 hB = *(float4*)&hsl[kx * 8 + 4];
#pragma unroll
                for (int i = 0; i < 8; ++i) {
                    const float w = Wreg[i][kk];
                    acc[i][0] += w * hA.x; acc[i][1] += w * hA.y;
                    acc[i][2] += w * hA.z; acc[i][3] += w * hA.w;
                    acc[i][4] += w * hB.x; acc[i][5] += w * hB.y;
                    acc[i][6] += w * hB.z; acc[i][7] += w * hB.w;
                }
            }
        }

        // ---- write partials: P[s][rt*64 + ((i*2+half)^(s&7))*4 + j]  (8-cyc optimal)
        {
            float* Pr = P + s * 512 + rt * 64;
            const int sw = s & 7;
#pragma unroll
            for (int i = 0; i < 8; ++i) {
                const int c0 = (i * 2) ^ sw;
                const int c1 = (i * 2 + 1) ^ sw;
                *(float4*)&Pr[c0 * 4] = make_float4(acc[i][0], acc[i][1], acc[i][2], acc[i][3]);
                *(float4*)&Pr[c1 * 4] = make_float4(acc[i][4], acc[i][5], acc[i][6], acc[i][7]);
            }
        }
        __syncthreads();

        // ---- reduce (conflict-free): outputs o1 = tid, o2 = tid + 256
        {
            float s1v = xv1, s2v = xv2;
#pragma unroll 8
            for (int ss = 0; ss < 32; ++ss) {
                const int swz = (ss & 7) << 2;
                const float* Prow = P + ss * 512;
                s1v += Prow[tid ^ swz];            // consecutive lanes ^ const -> bank perm
                s2v += Prow[(tid + 256) ^ swz];
            }
            const float a1 = sigmoidf_(s1v);                       // gates i / f
            const float a2 = isTanh ? tanhf(s2v) : sigmoidf_(s2v); // gates g / o
            act[tid] = a1;
            act[tid + 256] = a2;
        }
        __syncthreads();

        // ---- finalize: c,h for (uu = tid>>3, bl = tid&7); publish h
        if (tid < 128) {
            const float gi = act[tid];
            const float gf = act[tid + 128];
            const float gg = act[tid + 256];
            const float go = act[tid + 384];
            cst = gf * cst + gi * gg;
            const float h = go * tanhf(cst);
            const int uglob = ug * 16 + (tid >> 3);
            hsT[((size_t)t * 512 + uglob) * 64 + bg * 8 + (tid & 7)] = h;
            if (t < T_ - 1) {
                float* dst = hb + ((size_t)((t + 1) & 1) * BGN + bg) * 4096 + ug * 128 + tid;
                asm volatile("global_store_dword %0, %1, off sc0 sc1"
                             :: "v"(dst), "v"(h) : "memory");
            }
            asm volatile("s_waitcnt vmcnt(0)" ::: "memory");
        }

        // ---- bg-local barrier: per-WG flag store + 32-lane parallel poll
        if (t < T_ - 1) {
            __syncthreads();   // all h stores drained (per-wave vmcnt(0) above)
            if (tid == 0)
                __hip_atomic_store(myflag, t + 1, __ATOMIC_RELAXED,
                                   __HIP_MEMORY_SCOPE_AGENT);
            if (tid < 32) {
                while (__hip_atomic_load(bar + (bg * 32 + tid) * 8, __ATOMIC_RELAXED,
                                         __HIP_MEMORY_SCOPE_AGENT) < t + 1)
                    __builtin_amdgcn_s_sleep(1);
            }
            __syncthreads();
        }
    }
}

// ---------------------------------------------------------------------------
// K4: out[b][t] = sigmoid( dot(hsT[t][:][b], W_out[qshft[b][t]]) + b_out[..] )
// ---------------------------------------------------------------------------
__global__ __launch_bounds__(256) void out_gather2(const float* __restrict__ hsT,
                                                   const float* __restrict__ Wout,
                                                   const float* __restrict__ bout,
                                                   const int* __restrict__ qshft,
                                                   float* __restrict__ out) {
    __shared__ float red[4][64];
    int t = blockIdx.x;
    int b = threadIdx.x & 63, kg = threadIdx.x >> 6;
    int qs = qshft[b * 200 + t];
    const float* hp = hsT + (size_t)t * 512 * 64 + b;
    const float4* wp = (const float4*)(Wout + (size_t)qs * 512);
    float acc = 0.0f;
    int u0 = kg * 128;
#pragma unroll 8
    for (int u = u0; u < u0 + 128; u += 4) {
        float4 wv = wp[u >> 2];
        acc += hp[(size_t)(u + 0) * 64] * wv.x + hp[(size_t)(u + 1) * 64] * wv.y +
               hp[(size_t)(u + 2) * 64] * wv.z + hp[(size_t)(u + 3) * 64] * wv.w;
    }
    red[kg][b] = acc;
    __syncthreads();
    if (threadIdx.x < 64) {
        int bb = threadIdx.x;
        int qs2 = qshft[bb * 200 + t];
        float sum = red[0][bb] + red[1][bb] + red[2][bb] + red[3][bb];
        out[bb * 200 + t] = sigmoidf_(sum + bout[qs2]);
    }
}

// ---------------------------------------------------------------------------
extern "C" void kernel_launch(void* const* d_in, const int* in_sizes, int n_in,
                              void* d_out, int out_size, void* d_ws, size_t ws_size,
                              hipStream_t stream) {
    const int*   q    = (const int*)d_in[0];
    // d_in[1] = c (unused by the reference computation)
    const int*   r    = (const int*)d_in[2];
    const int*   qsft = (const int*)d_in[3];
    const float* emb  = (const float*)d_in[4];
    const float* Wih  = (const float*)d_in[5];
    const float* Whh  = (const float*)d_in[6];
    const float* bih  = (const float*)d_in[7];
    const float* bhh  = (const float*)d_in[8];
    const float* Wout = (const float*)d_in[9];
    const float* bout = (const float*)d_in[10];
    float* out = (float*)d_out;

    // workspace layout (bytes) — hsT aliases the dead xi region:
    //   [0, 8KB)        barrier flags (memset 0 every call; 32B spacing)
    //   [8KB, +256KB)   hb [2][8][512][8] f32 (memset 0: t=0 state)
    //   [+, +104.9MB)   xi4 [200][32][8][512]
    //   [+, +104.9MB)   X: xi [12800][2048] (early) / hsT [200][512][64] (late)
    //   total ~210 MB
    char* wsb = (char*)d_ws;
    int*   bar = (int*)wsb;
    float* hb  = (float*)(wsb + 8192);
    float* xi4 = (float*)(wsb + 8192 + 262144);
    float* xiX = (float*)(wsb + 8192 + 262144 + 104857600ull);
    float* xi  = xiX;   // live: xi_gemm -> xi_reshape
    float* hsT = xiX;   // live: lstm4 -> out_gather2 (xi dead by then)

    hipMemsetAsync(wsb, 0, 8192 + 262144, stream);

    xi_gemm<<<dim3(200, 32), 256, 0, stream>>>(q, r, emb, Wih, bih, bhh, xi);
    xi_reshape<<<dim3(200, 32), 256, 0, stream>>>(xi, xi4);

    hipFuncSetAttribute((const void*)lstm4,
                        hipFuncAttributeMaxDynamicSharedMemorySize, LSTM_SMEM);
    {
        const float* a0 = Whh; const float* a1 = xi4; float* a2 = hb;
        float* a3 = hsT; int* a4 = bar;
        void* ka[] = {(void*)&a0, (void*)&a1, (void*)&a2, (void*)&a3, (void*)&a4};
        hipError_t e = hipLaunchCooperativeKernel((const void*)lstm4, dim3(256),
                                                  dim3(256), ka, LSTM_SMEM, stream);
        if (e != hipSuccess) {
            // fallback: plain launch (256 WGs, 84KB LDS -> 1/CU, all co-resident)
            lstm4<<<256, 256, LSTM_SMEM, stream>>>(Whh, xi4, hb, hsT, bar);
        }
    }

    out_gather2<<<200, 256, 0, stream>>>(hsT, Wout, bout, qsft, out);
}